// Round 1
// baseline (130.692 us; speedup 1.0000x reference)
//
#include <hip/hip_runtime.h>

typedef unsigned int u32;
typedef unsigned short u16;
typedef __attribute__((ext_vector_type(8))) short bf16x8;
typedef __attribute__((ext_vector_type(4))) float f32x4;

#define T_TOK 12544   // 4*56*56
#define EMB   256
#define IMG   56
// SCALE * log2(e): softmax via exp2 is mathematically identical
#define SCALE2 0.25503486f
#define HALO  196
#define KSTR  40      // sK row stride (u16)
#define VTSTR 208     // sVT row stride (u16) — must stay %8==0 for b128 PV reads
#define PSTR  136     // sP row stride (u16): 128-col window + 8 pad

__device__ __forceinline__ u32 bf16_rtne(float f) {
    u32 u = __builtin_bit_cast(u32, f);
    return (u + 0x7fffu + ((u >> 16) & 1u)) >> 16;
}
__device__ __forceinline__ float bf16_to_f(u32 h) { return __builtin_bit_cast(float, h << 16); }

// async global->LDS, 16B/lane; LDS dest must be wave-uniform base + lane*16
#define GLD16(g, l) __builtin_amdgcn_global_load_lds( \
    (const __attribute__((address_space(1))) u32*)(g), \
    (__attribute__((address_space(3))) u32*)(l), 16, 0, 0)

// ---------------------------------------------------------------------------
// Convert: x -> bf16, qkv weights -> bf16 stacked [768][256], wo -> hi/lo.
// ---------------------------------------------------------------------------
__global__ __launch_bounds__(256) void convert_kernel(
    const float* __restrict__ x, const float* __restrict__ wq, const float* __restrict__ wk,
    const float* __restrict__ wv, const float* __restrict__ wo,
    u16* __restrict__ xb, u16* __restrict__ bsh,
    u16* __restrict__ boh, u16* __restrict__ bol) {
    const int i = blockIdx.x * 256 + threadIdx.x;
    const int NX4 = T_TOK * EMB / 4;   // 802816
    if (i < NX4) {
        const float4 f = ((const float4*)x)[i];
        const float vf[4] = {f.x, f.y, f.z, f.w};
        ushort4 hv;
        u16* hp = (u16*)&hv;
        #pragma unroll
        for (int c = 0; c < 4; ++c) hp[c] = (u16)bf16_rtne(vf[c]);
        ((ushort4*)xb)[i] = hv;
    } else {
        const int j = i - NX4;                 // < 65536
        const int w = j >> 14, widx = j & 16383;
        const float* src = (w == 0) ? wq : (w == 1) ? wk : (w == 2) ? wv : wo;
        const float4 f = ((const float4*)src)[widx];
        const float vf[4] = {f.x, f.y, f.z, f.w};
        if (w < 3) {
            ushort4 hv;
            u16* hp = (u16*)&hv;
            #pragma unroll
            for (int c = 0; c < 4; ++c) hp[c] = (u16)bf16_rtne(vf[c]);
            ((ushort4*)bsh)[(w << 14) + widx] = hv;
        } else {
            ushort4 hv, lv;
            u16* hp = (u16*)&hv; u16* lp = (u16*)&lv;
            #pragma unroll
            for (int c = 0; c < 4; ++c) {
                const u32 h = bf16_rtne(vf[c]);
                hp[c] = (u16)h;
                lp[c] = (u16)bf16_rtne(vf[c] - bf16_to_f(h));
            }
            ((ushort4*)boh)[widx] = hv;
            ((ushort4*)bol)[widx] = lv;
        }
    }
}

// ---------------------------------------------------------------------------
// QKV GEMM, 128x128 tile (grid (6,98) = 588 blocks), m97-style: 4 waves,
// each wave owns a 64x64 quadrant (acc 4x4), 16 MFMA : 8 ds_read_b128 per
// k-tile, GLD16 staging (4 per buffer), double-buffered, 1 barrier/k-tile.
// Output is HEAD-BLOCKED: q/k/v stored as [head][token][32] so the attention
// kernel's per-pixel reads are 64 B contiguous.
// ---------------------------------------------------------------------------
__global__ __launch_bounds__(256) void qkv_mfma(
    const u16* __restrict__ xb, const u16* __restrict__ bsh,
    const float* __restrict__ bq, const float* __restrict__ bk, const float* __restrict__ bv,
    u16* __restrict__ qb, u16* __restrict__ kb, u16* __restrict__ vb) {
    __shared__ __attribute__((aligned(16))) u16 sA[2][128 * 32];
    __shared__ __attribute__((aligned(16))) u16 sB[2][128 * 32];
    const int nBase = blockIdx.x * 128;            // 0..767 (stacked qkv)
    const int mBase = blockIdx.y * 128;
    const int tid = threadIdx.x, wv = tid >> 6, ln = tid & 63;
    const int lrow = ln & 15, lqd = ln >> 4;
    const int wr = wv >> 1, wc = wv & 1;           // wave quadrant (2x2)
    const int rA = tid >> 2, kcA = tid & 3;
    const size_t gA = (size_t)(mBase + rA) * EMB + kcA * 8;
    const size_t gB = (size_t)(nBase + rA) * EMB + kcA * 8;
    const int lA = wv * 512;                       // wave-uniform u16 base

    f32x4 acc[4][4];
    #pragma unroll
    for (int mi = 0; mi < 4; ++mi)
        #pragma unroll
        for (int ni = 0; ni < 4; ++ni) acc[mi][ni] = (f32x4){0.f, 0.f, 0.f, 0.f};

    GLD16(xb  + gA,            &sA[0][lA]);
    GLD16(xb  + gA + 64 * EMB, &sA[0][2048 + lA]);
    GLD16(bsh + gB,            &sB[0][lA]);
    GLD16(bsh + gB + 64 * EMB, &sB[0][2048 + lA]);

    for (int kt = 0; kt < 8; ++kt) {
        const int b = kt & 1;
        __syncthreads();
        if (kt < 7) {
            const int k0 = (kt + 1) * 32;
            GLD16(xb  + gA + k0,            &sA[b ^ 1][lA]);
            GLD16(xb  + gA + k0 + 64 * EMB, &sA[b ^ 1][2048 + lA]);
            GLD16(bsh + gB + k0,            &sB[b ^ 1][lA]);
            GLD16(bsh + gB + k0 + 64 * EMB, &sB[b ^ 1][2048 + lA]);
        }
        bf16x8 af[4], bfr[4];
        #pragma unroll
        for (int mi = 0; mi < 4; ++mi)
            af[mi] = *(const bf16x8*)&sA[b][(wr * 64 + mi * 16 + lrow) * 32 + lqd * 8];
        #pragma unroll
        for (int ni = 0; ni < 4; ++ni)
            bfr[ni] = *(const bf16x8*)&sB[b][(wc * 64 + ni * 16 + lrow) * 32 + lqd * 8];
        #pragma unroll
        for (int mi = 0; mi < 4; ++mi)
            #pragma unroll
            for (int ni = 0; ni < 4; ++ni)
                acc[mi][ni] = __builtin_amdgcn_mfma_f32_16x16x32_bf16(af[mi], bfr[ni], acc[mi][ni], 0, 0, 0);
    }

    const int which = nBase >> 8;   // 0=q, 1=k, 2=v (uniform: 128 | 256-group)
    const float* bias = (which == 0) ? bq : (which == 1) ? bk : bv;
    u16* dst = (which == 0) ? qb : (which == 1) ? kb : vb;
    #pragma unroll
    for (int ni = 0; ni < 4; ++ni) {
        const int cg = (nBase & 255) + wc * 64 + ni * 16;   // 16-aligned in [0,256)
        const int head = cg >> 5;
        const int d = (cg & 31) + lrow;                      // (cg&31) in {0,16}
        const float bz = bias[cg + lrow];
        u16* dh = dst + (size_t)head * T_TOK * 32;
        #pragma unroll
        for (int mi = 0; mi < 4; ++mi) {
            #pragma unroll
            for (int r = 0; r < 4; ++r) {
                const int row = mBase + wr * 64 + mi * 16 + lqd * 4 + r;
                dh[(size_t)row * 32 + d] = (u16)bf16_rtne(acc[mi][ni][r] + bz);
            }
        }
    }
}

// ---------------------------------------------------------------------------
// Out-projection, 64x64 tile (784 blocks), 3-pass split-bf16, GLD16,
// double-buffered, one barrier per k-tile.
// ---------------------------------------------------------------------------
__global__ __launch_bounds__(256) void out_mfma(
    const u16* __restrict__ aoh, const u16* __restrict__ aol,
    const u16* __restrict__ boh, const u16* __restrict__ bol,
    const float* __restrict__ bo, float* __restrict__ out) {
    __shared__ __attribute__((aligned(16))) u16 sAh[2][64 * 32];
    __shared__ __attribute__((aligned(16))) u16 sAl[2][64 * 32];
    __shared__ __attribute__((aligned(16))) u16 sBh[2][64 * 32];
    __shared__ __attribute__((aligned(16))) u16 sBl[2][64 * 32];
    const int nBase = blockIdx.x * 64;
    const int mBase = blockIdx.y * 64;
    const int tid = threadIdx.x, wv = tid >> 6, ln = tid & 63;
    const int lrow = ln & 15, lqd = ln >> 4;
    const int rA = tid >> 2, kcA = tid & 3;
    const size_t gA = (size_t)(mBase + rA) * EMB + kcA * 8;
    const size_t gB = (size_t)(nBase + rA) * EMB + kcA * 8;
    const int lA = wv * 64 * 8;

    f32x4 acc[4];
    #pragma unroll
    for (int mi = 0; mi < 4; ++mi) acc[mi] = (f32x4){0.f, 0.f, 0.f, 0.f};

    GLD16(aoh + gA, &sAh[0][lA]);
    GLD16(aol + gA, &sAl[0][lA]);
    GLD16(boh + gB, &sBh[0][lA]);
    GLD16(bol + gB, &sBl[0][lA]);

    for (int kt = 0; kt < 8; ++kt) {
        const int b = kt & 1;
        __syncthreads();
        if (kt < 7) {
            const int k0 = (kt + 1) * 32;
            GLD16(aoh + gA + k0, &sAh[b ^ 1][lA]);
            GLD16(aol + gA + k0, &sAl[b ^ 1][lA]);
            GLD16(boh + gB + k0, &sBh[b ^ 1][lA]);
            GLD16(bol + gB + k0, &sBl[b ^ 1][lA]);
        }
        bf16x8 ah[4], al[4];
        #pragma unroll
        for (int mi = 0; mi < 4; ++mi) {
            ah[mi] = *(const bf16x8*)&sAh[b][(mi * 16 + lrow) * 32 + lqd * 8];
            al[mi] = *(const bf16x8*)&sAl[b][(mi * 16 + lrow) * 32 + lqd * 8];
        }
        const bf16x8 bh = *(const bf16x8*)&sBh[b][(wv * 16 + lrow) * 32 + lqd * 8];
        const bf16x8 bl = *(const bf16x8*)&sBl[b][(wv * 16 + lrow) * 32 + lqd * 8];
        #pragma unroll
        for (int mi = 0; mi < 4; ++mi) {
            acc[mi] = __builtin_amdgcn_mfma_f32_16x16x32_bf16(ah[mi], bh, acc[mi], 0, 0, 0);
            acc[mi] = __builtin_amdgcn_mfma_f32_16x16x32_bf16(al[mi], bh, acc[mi], 0, 0, 0);
            acc[mi] = __builtin_amdgcn_mfma_f32_16x16x32_bf16(ah[mi], bl, acc[mi], 0, 0, 0);
        }
    }

    const int ncol = nBase + wv * 16 + lrow;
    const float bz = bo[ncol];
    #pragma unroll
    for (int mi = 0; mi < 4; ++mi) {
        #pragma unroll
        for (int r = 0; r < 4; ++r) {
            const int row = mBase + mi * 16 + lqd * 4 + r;
            out[(size_t)row * EMB + ncol] = acc[mi][r] + bz;
        }
    }
}

// ---------------------------------------------------------------------------
// Attention (MFMA, windowed): 256 thr = 4 waves = one (img, 8x8 tile, head).
// q/k/v are head-blocked [head][token][32] -> staging loads are 64 B
// contiguous per pixel (coalesced 1 KB/wave-instr vs 512 B-strided before).
// Wave w's 16 pixels only attend within halo cols 28w..28w+111, so each wave
// runs QK/PV over an aligned 128-col window base8=(28w)&~7 ({0,24,56,80}).
// Masked cols produce P=exp2(-1e30-m)=+0 exactly. LDS 30720 B -> 5 blk/CU.
// ---------------------------------------------------------------------------
__global__ __launch_bounds__(256, 5) void attn_kernel(
    const u16* __restrict__ qb, const u16* __restrict__ kb, const u16* __restrict__ vb,
    u16* __restrict__ aoh, u16* __restrict__ aol) {
    __shared__ __attribute__((aligned(16))) u16 smem[15360];   // 30720 B
    u16* sVT = smem;            // [32][VTSTR=208]  V^T (persists)
    u16* sK  = smem + 6656;     // [208][KSTR=40]   K halo, rows>=196 zero
    u16* sP  = smem + 6656;     // [4][16][PSTR=136] overlays sK after barrier 2

    const int tid = threadIdx.x;
    const int w = tid >> 6, ln = tid & 63;
    const int lrow = ln & 15, lqd = ln >> 4;
    const int img = blockIdx.z >> 3, head = blockIdx.z & 7;
    const int ty0 = blockIdx.y * 8, tx0 = blockIdx.x * 8;
    const int base8 = (28 * w) & ~7;   // {0, 24, 56, 80}

    const u16* kbh = kb + (size_t)head * (T_TOK * 32);
    const u16* vbh = vb + (size_t)head * (T_TOK * 32);
    const u16* qbh = qb + (size_t)head * (T_TOK * 32);

    // ---- stage K [p][d] (b128) and V transposed [d][p] (b16 scatter) ----
    for (int i = tid; i < 1664; i += 256) {
        const int mv = (i >= 832) ? 1 : 0;
        const int ii = i - 832 * mv;
        const int p = ii >> 2, c = ii & 3;
        const int pyh = p / 14, pxh = p - pyh * 14;
        const int gy = ty0 - 3 + pyh, gx = tx0 - 3 + pxh;
        const bool ok = (p < HALO) & ((unsigned)gy < 56u) & ((unsigned)gx < 56u);
        const size_t tt = (size_t)((img * IMG + gy) * IMG + gx) * 32;
        if (!mv) {
            u16* dstk = sK + p * KSTR + c * 8;
            if (ok) {
                *(uint4*)dstk = *(const uint4*)(kbh + tt + c * 8);
            } else {
                *(uint4*)dstk = (uint4){0u, 0u, 0u, 0u};
            }
        } else {
            u16* dv = sVT + (c * 8) * VTSTR + p;
            if (ok) {
                const uint4 u = *(const uint4*)(vbh + tt + c * 8);
                dv[0 * VTSTR] = (u16)(u.x & 0xffffu);
                dv[1 * VTSTR] = (u16)(u.x >> 16);
                dv[2 * VTSTR] = (u16)(u.y & 0xffffu);
                dv[3 * VTSTR] = (u16)(u.y >> 16);
                dv[4 * VTSTR] = (u16)(u.z & 0xffffu);
                dv[5 * VTSTR] = (u16)(u.z >> 16);
                dv[6 * VTSTR] = (u16)(u.w & 0xffffu);
                dv[7 * VTSTR] = (u16)(u.w >> 16);
            } else {
                #pragma unroll
                for (int j = 0; j < 8; ++j) dv[j * VTSTR] = 0;
            }
        }
    }

    // ---- Q A-fragment straight from global (bf16, head-blocked) ----
    const int mpix = w * 16 + lrow;
    const int qpy = mpix >> 3, qpx = mpix & 7;
    const size_t qtok = ((size_t)img * IMG + ty0 + qpy) * IMG + tx0 + qpx;
    const bf16x8 aq = *(const bf16x8*)&qbh[qtok * 32 + lqd * 8];
    __syncthreads();

    // ---- QK: 8 N-tiles over this wave's window base8..base8+127 ----
    f32x4 ct[8];
    #pragma unroll
    for (int t = 0; t < 8; ++t) ct[t] = (f32x4){0.f, 0.f, 0.f, 0.f};
    #pragma unroll
    for (int t = 0; t < 8; ++t) {
        const bf16x8 bk = *(const bf16x8*)&sK[(base8 + t * 16 + lrow) * KSTR + lqd * 8];
        ct[t] = __builtin_amdgcn_mfma_f32_16x16x32_bf16(aq, bk, ct[t], 0, 0, 0);
    }

    // ---- mask + softmax in C layout (row = lqd*4+r, col = base8+16t+lrow) --
    int pys[4], pxs[4];
    #pragma unroll
    for (int r = 0; r < 4; ++r) {
        const int row = lqd * 4 + r;
        pys[r] = 2 * w + (row >> 3);
        pxs[r] = row & 7;
    }
    float mr4[4] = {-1e30f, -1e30f, -1e30f, -1e30f};
    #pragma unroll
    for (int t = 0; t < 8; ++t) {
        const int col = base8 + t * 16 + lrow;
        const int hy = col / 14, hx = col - 14 * hy;
        const bool okc = (col < HALO);
        #pragma unroll
        for (int r = 0; r < 4; ++r) {
            const bool ok = ((unsigned)(hy - pys[r]) < 7u) &
                            ((unsigned)(hx - pxs[r]) < 7u) & okc;
            const float lv = ok ? ct[t][r] * SCALE2 : -1e30f;
            ct[t][r] = lv;
            mr4[r] = fmaxf(mr4[r], lv);
        }
    }
    #pragma unroll
    for (int r = 0; r < 4; ++r) {
        float m = mr4[r];
        m = fmaxf(m, __shfl_xor(m, 1));
        m = fmaxf(m, __shfl_xor(m, 2));
        m = fmaxf(m, __shfl_xor(m, 4));
        m = fmaxf(m, __shfl_xor(m, 8));
        mr4[r] = m;
    }
    float sr4[4] = {0.f, 0.f, 0.f, 0.f};
    #pragma unroll
    for (int t = 0; t < 8; ++t)
        #pragma unroll
        for (int r = 0; r < 4; ++r) {
            const float e = exp2f(ct[t][r] - mr4[r]);
            ct[t][r] = e;
            sr4[r] += e;
        }
    #pragma unroll
    for (int r = 0; r < 4; ++r) {
        float s = sr4[r];
        s += __shfl_xor(s, 1);
        s += __shfl_xor(s, 2);
        s += __shfl_xor(s, 4);
        s += __shfl_xor(s, 8);
        sr4[r] = 1.0f / s;
    }

    __syncthreads();   // all QK reads of sK done; safe to overlay with P

    // ---- P (bf16) to LDS: 8 tiles x 16 = the wave's 128-col window ----
    u16* sPw = sP + w * 16 * PSTR;
    #pragma unroll
    for (int t = 0; t < 8; ++t)
        #pragma unroll
        for (int r = 0; r < 4; ++r)
            sPw[(lqd * 4 + r) * PSTR + t * 16 + lrow] = (u16)bf16_rtne(ct[t][r]);

    // ---- PV: O[16][32] = P[16x128] . VT[32 rows, window cols]^T ----
    f32x4 o0 = (f32x4){0.f, 0.f, 0.f, 0.f};
    f32x4 o1 = (f32x4){0.f, 0.f, 0.f, 0.f};
    #pragma unroll
    for (int ks = 0; ks < 4; ++ks) {
        const bf16x8 ap  = *(const bf16x8*)&sPw[lrow * PSTR + ks * 32 + lqd * 8];
        const bf16x8 bv0 = *(const bf16x8*)&sVT[lrow * VTSTR + base8 + ks * 32 + lqd * 8];
        const bf16x8 bv1 = *(const bf16x8*)&sVT[(16 + lrow) * VTSTR + base8 + ks * 32 + lqd * 8];
        o0 = __builtin_amdgcn_mfma_f32_16x16x32_bf16(ap, bv0, o0, 0, 0, 0);
        o1 = __builtin_amdgcn_mfma_f32_16x16x32_bf16(ap, bv1, o1, 0, 0, 0);
    }

    // ---- epilogue: scale by 1/s, split-bf16, store ----
    #pragma unroll
    for (int r = 0; r < 4; ++r) {
        const int row = lqd * 4 + r;
        const int opy = 2 * w + (row >> 3), opx = row & 7;
        const size_t ot = ((size_t)img * IMG + ty0 + opy) * IMG + tx0 + opx;
        const float inv = sr4[r];
        const float v0 = o0[r] * inv;
        const float v1 = o1[r] * inv;
        const size_t base = ot * EMB + head * 32;
        const u32 h0 = bf16_rtne(v0);
        aoh[base + lrow] = (u16)h0;
        aol[base + lrow] = (u16)bf16_rtne(v0 - bf16_to_f(h0));
        const u32 h1 = bf16_rtne(v1);
        aoh[base + 16 + lrow] = (u16)h1;
        aol[base + 16 + lrow] = (u16)bf16_rtne(v1 - bf16_to_f(h1));
    }
}

extern "C" void kernel_launch(void* const* d_in, const int* in_sizes, int n_in,
                              void* d_out, int out_size, void* d_ws, size_t ws_size,
                              hipStream_t stream) {
    const float* x  = (const float*)d_in[0];
    const float* wq = (const float*)d_in[1];
    const float* wk = (const float*)d_in[2];
    const float* wv = (const float*)d_in[3];
    const float* wo = (const float*)d_in[4];
    const float* bq = (const float*)d_in[5];
    const float* bk = (const float*)d_in[6];
    const float* bv = (const float*)d_in[7];
    const float* bo = (const float*)d_in[8];
    float* out = (float*)d_out;

    char* ws = (char*)d_ws;
    u16* xb  = (u16*)(ws);               // 6,422,528 B  bf16 x
    u16* qb  = (u16*)(ws +  6422528);    // 6,422,528 B  head-blocked [8][12544][32]
    u16* kb  = (u16*)(ws + 12845056);    // 6,422,528 B  head-blocked
    u16* vb  = (u16*)(ws + 19267584);    // 6,422,528 B  head-blocked
    u16* aoh = (u16*)(ws + 25690112);    // 6,422,528 B
    u16* aol = (u16*)(ws + 32112640);    // 6,422,528 B
    u16* bsh = (u16*)(ws + 38535168);    // 393,216 B  stacked qkv weights bf16
    u16* boh = (u16*)(ws + 38928384);    // 131,072 B  wo hi
    u16* bol = (u16*)(ws + 39059456);    // 131,072 B  wo lo -> 39,190,528 B

    convert_kernel<<<3392, 256, 0, stream>>>(x, wq, wk, wv, wo, xb, bsh, boh, bol);
    qkv_mfma<<<dim3(6, 98), 256, 0, stream>>>(xb, bsh, bq, bk, bv, qb, kb, vb);
    attn_kernel<<<dim3(7, 7, 32), 256, 0, stream>>>(qb, kb, vb, aoh, aol);
    out_mfma<<<dim3(4, 196), 256, 0, stream>>>(aoh, aol, boh, bol, bo, out);
}

// Round 2
// 121.891 us; speedup vs baseline: 1.0722x; 1.0722x over previous
//
#include <hip/hip_runtime.h>

typedef unsigned int u32;
typedef unsigned short u16;
typedef _Float16 f16;
typedef __attribute__((ext_vector_type(8))) _Float16 f16x8;
typedef __attribute__((ext_vector_type(4))) float f32x4;

#define T_TOK 12544   // 4*56*56
#define EMB   256
#define IMG   56
// SCALE * log2(e): softmax via exp2 is mathematically identical
#define SCALE2 0.25503486f
#define HALO  196
#define KSTR  40      // sK row stride (u16)
#define VTSTR 208     // sVT row stride (u16) — must stay %8==0 for b128 PV reads
#define PSTR  136     // sP row stride (u16): 128-col window + 8 pad

__device__ __forceinline__ u16 f16b(float f) {
    const f16 h = (f16)f;                 // v_cvt_f16_f32, RTNE
    return __builtin_bit_cast(u16, h);
}

// async global->LDS, 16B/lane; LDS dest must be wave-uniform base + lane*16
#define GLD16(g, l) __builtin_amdgcn_global_load_lds( \
    (const __attribute__((address_space(1))) u32*)(g), \
    (__attribute__((address_space(3))) u32*)(l), 16, 0, 0)

// ---------------------------------------------------------------------------
// Convert: x -> f16, qkv weights -> f16 stacked [768][256], wo -> f16.
// ---------------------------------------------------------------------------
__global__ __launch_bounds__(256) void convert_kernel(
    const float* __restrict__ x, const float* __restrict__ wq, const float* __restrict__ wk,
    const float* __restrict__ wv, const float* __restrict__ wo,
    u16* __restrict__ xb, u16* __restrict__ wsh, u16* __restrict__ woh) {
    const int i = blockIdx.x * 256 + threadIdx.x;
    const int NX4 = T_TOK * EMB / 4;   // 802816
    if (i < NX4) {
        const float4 f = ((const float4*)x)[i];
        ushort4 hv;
        hv.x = f16b(f.x); hv.y = f16b(f.y); hv.z = f16b(f.z); hv.w = f16b(f.w);
        ((ushort4*)xb)[i] = hv;
    } else {
        const int j = i - NX4;                 // < 65536
        const int w = j >> 14, widx = j & 16383;
        const float* src = (w == 0) ? wq : (w == 1) ? wk : (w == 2) ? wv : wo;
        const float4 f = ((const float4*)src)[widx];
        ushort4 hv;
        hv.x = f16b(f.x); hv.y = f16b(f.y); hv.z = f16b(f.z); hv.w = f16b(f.w);
        if (w < 3) ((ushort4*)wsh)[(w << 14) + widx] = hv;
        else       ((ushort4*)woh)[widx] = hv;
    }
}

// ---------------------------------------------------------------------------
// QKV GEMM, 128x128 tile (grid (6,98) = 588 blocks): 4 waves, each wave owns
// a 64x64 quadrant (acc 4x4), 16 MFMA : 8 ds_read_b128 per k-tile, GLD16
// staging, double-buffered, 1 barrier/k-tile. Output HEAD-BLOCKED
// [head][token][32] so attention staging reads 64 B contiguous per pixel.
// ---------------------------------------------------------------------------
__global__ __launch_bounds__(256) void qkv_mfma(
    const u16* __restrict__ xb, const u16* __restrict__ wsh,
    const float* __restrict__ bq, const float* __restrict__ bk, const float* __restrict__ bv,
    u16* __restrict__ qb, u16* __restrict__ kb, u16* __restrict__ vb) {
    __shared__ __attribute__((aligned(16))) u16 sA[2][128 * 32];
    __shared__ __attribute__((aligned(16))) u16 sB[2][128 * 32];
    const int nBase = blockIdx.x * 128;            // 0..767 (stacked qkv)
    const int mBase = blockIdx.y * 128;
    const int tid = threadIdx.x, wv = tid >> 6, ln = tid & 63;
    const int lrow = ln & 15, lqd = ln >> 4;
    const int wr = wv >> 1, wc = wv & 1;           // wave quadrant (2x2)
    const int rA = tid >> 2, kcA = tid & 3;
    const size_t gA = (size_t)(mBase + rA) * EMB + kcA * 8;
    const size_t gB = (size_t)(nBase + rA) * EMB + kcA * 8;
    const int lA = wv * 512;                       // wave-uniform u16 base

    f32x4 acc[4][4];
    #pragma unroll
    for (int mi = 0; mi < 4; ++mi)
        #pragma unroll
        for (int ni = 0; ni < 4; ++ni) acc[mi][ni] = (f32x4){0.f, 0.f, 0.f, 0.f};

    GLD16(xb  + gA,            &sA[0][lA]);
    GLD16(xb  + gA + 64 * EMB, &sA[0][2048 + lA]);
    GLD16(wsh + gB,            &sB[0][lA]);
    GLD16(wsh + gB + 64 * EMB, &sB[0][2048 + lA]);

    for (int kt = 0; kt < 8; ++kt) {
        const int b = kt & 1;
        __syncthreads();
        if (kt < 7) {
            const int k0 = (kt + 1) * 32;
            GLD16(xb  + gA + k0,            &sA[b ^ 1][lA]);
            GLD16(xb  + gA + k0 + 64 * EMB, &sA[b ^ 1][2048 + lA]);
            GLD16(wsh + gB + k0,            &sB[b ^ 1][lA]);
            GLD16(wsh + gB + k0 + 64 * EMB, &sB[b ^ 1][2048 + lA]);
        }
        f16x8 af[4], bfr[4];
        #pragma unroll
        for (int mi = 0; mi < 4; ++mi)
            af[mi] = *(const f16x8*)&sA[b][(wr * 64 + mi * 16 + lrow) * 32 + lqd * 8];
        #pragma unroll
        for (int ni = 0; ni < 4; ++ni)
            bfr[ni] = *(const f16x8*)&sB[b][(wc * 64 + ni * 16 + lrow) * 32 + lqd * 8];
        #pragma unroll
        for (int mi = 0; mi < 4; ++mi)
            #pragma unroll
            for (int ni = 0; ni < 4; ++ni)
                acc[mi][ni] = __builtin_amdgcn_mfma_f32_16x16x32_f16(af[mi], bfr[ni], acc[mi][ni], 0, 0, 0);
    }

    const int which = nBase >> 8;   // 0=q, 1=k, 2=v (uniform: 128-tile within 256-group)
    const float* bias = (which == 0) ? bq : (which == 1) ? bk : bv;
    u16* dst = (which == 0) ? qb : (which == 1) ? kb : vb;
    #pragma unroll
    for (int ni = 0; ni < 4; ++ni) {
        const int cg = (nBase & 255) + wc * 64 + ni * 16;   // 16-aligned in [0,256)
        const int head = cg >> 5;
        const int d = (cg & 31) + lrow;                      // (cg&31) in {0,16}
        const float bz = bias[cg + lrow];
        u16* dh = dst + (size_t)head * T_TOK * 32;
        #pragma unroll
        for (int mi = 0; mi < 4; ++mi) {
            #pragma unroll
            for (int r = 0; r < 4; ++r) {
                const int row = mBase + wr * 64 + mi * 16 + lqd * 4 + r;
                dh[(size_t)row * 32 + d] = f16b(acc[mi][ni][r] + bz);
            }
        }
    }
}

// ---------------------------------------------------------------------------
// Out-projection, 64x64 tile (784 blocks), single-pass f16 MFMA, GLD16,
// double-buffered, one barrier per k-tile.
// ---------------------------------------------------------------------------
__global__ __launch_bounds__(256) void out_mfma(
    const u16* __restrict__ ao, const u16* __restrict__ woh,
    const float* __restrict__ bo, float* __restrict__ out) {
    __shared__ __attribute__((aligned(16))) u16 sA[2][64 * 32];
    __shared__ __attribute__((aligned(16))) u16 sB[2][64 * 32];
    const int nBase = blockIdx.x * 64;
    const int mBase = blockIdx.y * 64;
    const int tid = threadIdx.x, wv = tid >> 6, ln = tid & 63;
    const int lrow = ln & 15, lqd = ln >> 4;
    const int rA = tid >> 2, kcA = tid & 3;
    const size_t gA = (size_t)(mBase + rA) * EMB + kcA * 8;
    const size_t gB = (size_t)(nBase + rA) * EMB + kcA * 8;
    const int lA = wv * 512;

    f32x4 acc[4];
    #pragma unroll
    for (int mi = 0; mi < 4; ++mi) acc[mi] = (f32x4){0.f, 0.f, 0.f, 0.f};

    GLD16(ao  + gA, &sA[0][lA]);
    GLD16(woh + gB, &sB[0][lA]);

    for (int kt = 0; kt < 8; ++kt) {
        const int b = kt & 1;
        __syncthreads();
        if (kt < 7) {
            const int k0 = (kt + 1) * 32;
            GLD16(ao  + gA + k0, &sA[b ^ 1][lA]);
            GLD16(woh + gB + k0, &sB[b ^ 1][lA]);
        }
        f16x8 af[4];
        #pragma unroll
        for (int mi = 0; mi < 4; ++mi)
            af[mi] = *(const f16x8*)&sA[b][(mi * 16 + lrow) * 32 + lqd * 8];
        const f16x8 bf = *(const f16x8*)&sB[b][(wv * 16 + lrow) * 32 + lqd * 8];
        #pragma unroll
        for (int mi = 0; mi < 4; ++mi)
            acc[mi] = __builtin_amdgcn_mfma_f32_16x16x32_f16(af[mi], bf, acc[mi], 0, 0, 0);
    }

    const int ncol = nBase + wv * 16 + lrow;
    const float bz = bo[ncol];
    #pragma unroll
    for (int mi = 0; mi < 4; ++mi) {
        #pragma unroll
        for (int r = 0; r < 4; ++r) {
            const int row = mBase + mi * 16 + lqd * 4 + r;
            out[(size_t)row * EMB + ncol] = acc[mi][r] + bz;
        }
    }
}

// ---------------------------------------------------------------------------
// Attention (MFMA, windowed): 256 thr = 4 waves = one (img, 8x8 tile, head).
// q/k/v head-blocked [head][token][32] f16. Wave w's 16 pixels attend within
// halo cols 28w..28w+111; each wave runs QK/PV over an aligned 128-col window
// base8=(28w)&~7 ({0,24,56,80}). Masked cols give P=exp2(-1e30-m)=+0 exactly.
// Single f16 output buffer ao [tok][256]. LDS 30720 B -> 5 blk/CU.
// ---------------------------------------------------------------------------
__global__ __launch_bounds__(256, 5) void attn_kernel(
    const u16* __restrict__ qb, const u16* __restrict__ kb, const u16* __restrict__ vb,
    u16* __restrict__ ao) {
    __shared__ __attribute__((aligned(16))) u16 smem[15360];   // 30720 B
    u16* sVT = smem;            // [32][VTSTR=208]  V^T (persists)
    u16* sK  = smem + 6656;     // [208][KSTR=40]   K halo, rows>=196 zero
    u16* sP  = smem + 6656;     // [4][16][PSTR=136] overlays sK after barrier 2

    const int tid = threadIdx.x;
    const int w = tid >> 6, ln = tid & 63;
    const int lrow = ln & 15, lqd = ln >> 4;
    const int img = blockIdx.z >> 3, head = blockIdx.z & 7;
    const int ty0 = blockIdx.y * 8, tx0 = blockIdx.x * 8;
    const int base8 = (28 * w) & ~7;   // {0, 24, 56, 80}

    const u16* kbh = kb + (size_t)head * (T_TOK * 32);
    const u16* vbh = vb + (size_t)head * (T_TOK * 32);
    const u16* qbh = qb + (size_t)head * (T_TOK * 32);

    // ---- stage K [p][d] (b128) and V transposed [d][p] (b16 scatter) ----
    for (int i = tid; i < 1664; i += 256) {
        const int mv = (i >= 832) ? 1 : 0;
        const int ii = i - 832 * mv;
        const int p = ii >> 2, c = ii & 3;
        const int pyh = p / 14, pxh = p - pyh * 14;
        const int gy = ty0 - 3 + pyh, gx = tx0 - 3 + pxh;
        const bool ok = (p < HALO) & ((unsigned)gy < 56u) & ((unsigned)gx < 56u);
        const size_t tt = (size_t)((img * IMG + gy) * IMG + gx) * 32;
        if (!mv) {
            u16* dstk = sK + p * KSTR + c * 8;
            if (ok) {
                *(uint4*)dstk = *(const uint4*)(kbh + tt + c * 8);
            } else {
                *(uint4*)dstk = (uint4){0u, 0u, 0u, 0u};
            }
        } else {
            u16* dv = sVT + (c * 8) * VTSTR + p;
            if (ok) {
                const uint4 u = *(const uint4*)(vbh + tt + c * 8);
                dv[0 * VTSTR] = (u16)(u.x & 0xffffu);
                dv[1 * VTSTR] = (u16)(u.x >> 16);
                dv[2 * VTSTR] = (u16)(u.y & 0xffffu);
                dv[3 * VTSTR] = (u16)(u.y >> 16);
                dv[4 * VTSTR] = (u16)(u.z & 0xffffu);
                dv[5 * VTSTR] = (u16)(u.z >> 16);
                dv[6 * VTSTR] = (u16)(u.w & 0xffffu);
                dv[7 * VTSTR] = (u16)(u.w >> 16);
            } else {
                #pragma unroll
                for (int j = 0; j < 8; ++j) dv[j * VTSTR] = 0;
            }
        }
    }

    // ---- Q A-fragment straight from global (f16, head-blocked) ----
    const int mpix = w * 16 + lrow;
    const int qpy = mpix >> 3, qpx = mpix & 7;
    const size_t qtok = ((size_t)img * IMG + ty0 + qpy) * IMG + tx0 + qpx;
    const f16x8 aq = *(const f16x8*)&qbh[qtok * 32 + lqd * 8];
    __syncthreads();

    // ---- QK: 8 N-tiles over this wave's window base8..base8+127 ----
    f32x4 ct[8];
    #pragma unroll
    for (int t = 0; t < 8; ++t) ct[t] = (f32x4){0.f, 0.f, 0.f, 0.f};
    #pragma unroll
    for (int t = 0; t < 8; ++t) {
        const f16x8 bk = *(const f16x8*)&sK[(base8 + t * 16 + lrow) * KSTR + lqd * 8];
        ct[t] = __builtin_amdgcn_mfma_f32_16x16x32_f16(aq, bk, ct[t], 0, 0, 0);
    }

    // ---- mask + softmax in C layout (row = lqd*4+r, col = base8+16t+lrow) --
    int pys[4], pxs[4];
    #pragma unroll
    for (int r = 0; r < 4; ++r) {
        const int row = lqd * 4 + r;
        pys[r] = 2 * w + (row >> 3);
        pxs[r] = row & 7;
    }
    float mr4[4] = {-1e30f, -1e30f, -1e30f, -1e30f};
    #pragma unroll
    for (int t = 0; t < 8; ++t) {
        const int col = base8 + t * 16 + lrow;
        const int hy = col / 14, hx = col - 14 * hy;
        const bool okc = (col < HALO);
        #pragma unroll
        for (int r = 0; r < 4; ++r) {
            const bool ok = ((unsigned)(hy - pys[r]) < 7u) &
                            ((unsigned)(hx - pxs[r]) < 7u) & okc;
            const float lv = ok ? ct[t][r] * SCALE2 : -1e30f;
            ct[t][r] = lv;
            mr4[r] = fmaxf(mr4[r], lv);
        }
    }
    #pragma unroll
    for (int r = 0; r < 4; ++r) {
        float m = mr4[r];
        m = fmaxf(m, __shfl_xor(m, 1));
        m = fmaxf(m, __shfl_xor(m, 2));
        m = fmaxf(m, __shfl_xor(m, 4));
        m = fmaxf(m, __shfl_xor(m, 8));
        mr4[r] = m;
    }
    float sr4[4] = {0.f, 0.f, 0.f, 0.f};
    #pragma unroll
    for (int t = 0; t < 8; ++t)
        #pragma unroll
        for (int r = 0; r < 4; ++r) {
            const float e = exp2f(ct[t][r] - mr4[r]);
            ct[t][r] = e;
            sr4[r] += e;
        }
    #pragma unroll
    for (int r = 0; r < 4; ++r) {
        float s = sr4[r];
        s += __shfl_xor(s, 1);
        s += __shfl_xor(s, 2);
        s += __shfl_xor(s, 4);
        s += __shfl_xor(s, 8);
        sr4[r] = 1.0f / s;
    }

    __syncthreads();   // all QK reads of sK done; safe to overlay with P

    // ---- P (f16) to LDS: 8 tiles x 16 = the wave's 128-col window ----
    u16* sPw = sP + w * 16 * PSTR;
    #pragma unroll
    for (int t = 0; t < 8; ++t)
        #pragma unroll
        for (int r = 0; r < 4; ++r)
            sPw[(lqd * 4 + r) * PSTR + t * 16 + lrow] = f16b(ct[t][r]);

    // ---- PV: O[16][32] = P[16x128] . VT[32 rows, window cols]^T ----
    f32x4 o0 = (f32x4){0.f, 0.f, 0.f, 0.f};
    f32x4 o1 = (f32x4){0.f, 0.f, 0.f, 0.f};
    #pragma unroll
    for (int ks = 0; ks < 4; ++ks) {
        const f16x8 ap  = *(const f16x8*)&sPw[lrow * PSTR + ks * 32 + lqd * 8];
        const f16x8 bv0 = *(const f16x8*)&sVT[lrow * VTSTR + base8 + ks * 32 + lqd * 8];
        const f16x8 bv1 = *(const f16x8*)&sVT[(16 + lrow) * VTSTR + base8 + ks * 32 + lqd * 8];
        o0 = __builtin_amdgcn_mfma_f32_16x16x32_f16(ap, bv0, o0, 0, 0, 0);
        o1 = __builtin_amdgcn_mfma_f32_16x16x32_f16(ap, bv1, o1, 0, 0, 0);
    }

    // ---- epilogue: scale by 1/s, f16, single buffer store ----
    #pragma unroll
    for (int r = 0; r < 4; ++r) {
        const int row = lqd * 4 + r;
        const int opy = 2 * w + (row >> 3), opx = row & 7;
        const size_t ot = ((size_t)img * IMG + ty0 + opy) * IMG + tx0 + opx;
        const float inv = sr4[r];
        const size_t base = ot * EMB + head * 32;
        ao[base + lrow]      = f16b(o0[r] * inv);
        ao[base + 16 + lrow] = f16b(o1[r] * inv);
    }
}

extern "C" void kernel_launch(void* const* d_in, const int* in_sizes, int n_in,
                              void* d_out, int out_size, void* d_ws, size_t ws_size,
                              hipStream_t stream) {
    const float* x  = (const float*)d_in[0];
    const float* wq = (const float*)d_in[1];
    const float* wk = (const float*)d_in[2];
    const float* wv = (const float*)d_in[3];
    const float* wo = (const float*)d_in[4];
    const float* bq = (const float*)d_in[5];
    const float* bk = (const float*)d_in[6];
    const float* bv = (const float*)d_in[7];
    const float* bo = (const float*)d_in[8];
    float* out = (float*)d_out;

    char* ws = (char*)d_ws;
    u16* xb  = (u16*)(ws);               // 6,422,528 B  f16 x
    u16* qb  = (u16*)(ws +  6422528);    // 6,422,528 B  head-blocked [8][12544][32]
    u16* kb  = (u16*)(ws + 12845056);    // 6,422,528 B  head-blocked
    u16* vb  = (u16*)(ws + 19267584);    // 6,422,528 B  head-blocked
    u16* ao  = (u16*)(ws + 25690112);    // 6,422,528 B  attn out f16 [tok][256]
    u16* wsh = (u16*)(ws + 32112640);    // 393,216 B  stacked qkv weights f16
    u16* woh = (u16*)(ws + 32505856);    // 131,072 B  wo f16 -> 32,636,928 B

    convert_kernel<<<3392, 256, 0, stream>>>(x, wq, wk, wv, wo, xb, wsh, woh);
    qkv_mfma<<<dim3(6, 98), 256, 0, stream>>>(xb, wsh, bq, bk, bv, qb, kb, vb);
    attn_kernel<<<dim3(7, 7, 32), 256, 0, stream>>>(qb, kb, vb, ao);
    out_mfma<<<dim3(4, 196), 256, 0, stream>>>(ao, woh, bo, out);
}

// Round 3
// 120.752 us; speedup vs baseline: 1.0823x; 1.0094x over previous
//
#include <hip/hip_runtime.h>

typedef unsigned int u32;
typedef unsigned short u16;
typedef _Float16 f16;
typedef __attribute__((ext_vector_type(8))) _Float16 f16x8;
typedef __attribute__((ext_vector_type(4))) float f32x4;

#define T_TOK 12544   // 4*56*56
#define EMB   256
#define IMG   56
// SCALE * log2(e): softmax via exp2 is mathematically identical
#define SCALE2 0.25503486f
#define HALO  196
#define KSTR  40      // sK row stride (u16)
#define VTSTR 208     // sVT row stride (u16) — must stay %8==0 for b128 PV reads
#define PSTR  136     // sP row stride (u16): 128-col window + 8 pad (17x16B rows)

__device__ __forceinline__ u16 f16b(float f) {
    const f16 h = (f16)f;                 // v_cvt_f16_f32, RTNE
    return __builtin_bit_cast(u16, h);
}

// async global->LDS, 16B/lane; LDS dest must be wave-uniform base + lane*16
#define GLD16(g, l) __builtin_amdgcn_global_load_lds( \
    (const __attribute__((address_space(1))) u32*)(g), \
    (__attribute__((address_space(3))) u32*)(l), 16, 0, 0)

// ---------------------------------------------------------------------------
// Convert: x -> f16, qkv weights -> f16 stacked [768][256], wo -> f16.
// ---------------------------------------------------------------------------
__global__ __launch_bounds__(256) void convert_kernel(
    const float* __restrict__ x, const float* __restrict__ wq, const float* __restrict__ wk,
    const float* __restrict__ wv, const float* __restrict__ wo,
    u16* __restrict__ xb, u16* __restrict__ wsh, u16* __restrict__ woh) {
    const int i = blockIdx.x * 256 + threadIdx.x;
    const int NX4 = T_TOK * EMB / 4;   // 802816
    if (i < NX4) {
        const float4 f = ((const float4*)x)[i];
        ushort4 hv;
        hv.x = f16b(f.x); hv.y = f16b(f.y); hv.z = f16b(f.z); hv.w = f16b(f.w);
        ((ushort4*)xb)[i] = hv;
    } else {
        const int j = i - NX4;                 // < 65536
        const int w = j >> 14, widx = j & 16383;
        const float* src = (w == 0) ? wq : (w == 1) ? wk : (w == 2) ? wv : wo;
        const float4 f = ((const float4*)src)[widx];
        ushort4 hv;
        hv.x = f16b(f.x); hv.y = f16b(f.y); hv.z = f16b(f.z); hv.w = f16b(f.w);
        if (w < 3) ((ushort4*)wsh)[(w << 14) + widx] = hv;
        else       ((ushort4*)woh)[widx] = hv;
    }
}

// ---------------------------------------------------------------------------
// QKV GEMM, 128x128 tile (588 blocks): 4 waves, each wave a 64x64 quadrant
// (acc 4x4), GLD16 staging, double-buffered, 1 barrier/k-tile. XCD-chunked
// bijective block swizzle (588 = 4x74 + 4x73) so ~12 consecutive m-slabs
// with all 6 n-groups land on one XCD -> x re-reads become XCD-L2 hits.
// Output HEAD-BLOCKED [head][token][32].
// ---------------------------------------------------------------------------
__global__ __launch_bounds__(256) void qkv_mfma(
    const u16* __restrict__ xb, const u16* __restrict__ wsh,
    const float* __restrict__ bq, const float* __restrict__ bk, const float* __restrict__ bv,
    u16* __restrict__ qb, u16* __restrict__ kb, u16* __restrict__ vb) {
    __shared__ __attribute__((aligned(16))) u16 sA[2][128 * 32];
    __shared__ __attribute__((aligned(16))) u16 sB[2][128 * 32];
    const int bid = blockIdx.y * 6 + blockIdx.x;
    const int xcd = bid & 7, loc = bid >> 3;
    const int work = (xcd < 4 ? xcd * 74 : 296 + (xcd - 4) * 73) + loc;
    const int nBase = (work % 6) * 128;            // 0..767 (stacked qkv)
    const int mBase = (work / 6) * 128;
    const int tid = threadIdx.x, wv = tid >> 6, ln = tid & 63;
    const int lrow = ln & 15, lqd = ln >> 4;
    const int wr = wv >> 1, wc = wv & 1;           // wave quadrant (2x2)
    const int rA = tid >> 2, kcA = tid & 3;
    const size_t gA = (size_t)(mBase + rA) * EMB + kcA * 8;
    const size_t gB = (size_t)(nBase + rA) * EMB + kcA * 8;
    const int lA = wv * 512;                       // wave-uniform u16 base

    f32x4 acc[4][4];
    #pragma unroll
    for (int mi = 0; mi < 4; ++mi)
        #pragma unroll
        for (int ni = 0; ni < 4; ++ni) acc[mi][ni] = (f32x4){0.f, 0.f, 0.f, 0.f};

    GLD16(xb  + gA,            &sA[0][lA]);
    GLD16(xb  + gA + 64 * EMB, &sA[0][2048 + lA]);
    GLD16(wsh + gB,            &sB[0][lA]);
    GLD16(wsh + gB + 64 * EMB, &sB[0][2048 + lA]);

    for (int kt = 0; kt < 8; ++kt) {
        const int b = kt & 1;
        __syncthreads();
        if (kt < 7) {
            const int k0 = (kt + 1) * 32;
            GLD16(xb  + gA + k0,            &sA[b ^ 1][lA]);
            GLD16(xb  + gA + k0 + 64 * EMB, &sA[b ^ 1][2048 + lA]);
            GLD16(wsh + gB + k0,            &sB[b ^ 1][lA]);
            GLD16(wsh + gB + k0 + 64 * EMB, &sB[b ^ 1][2048 + lA]);
        }
        f16x8 af[4], bfr[4];
        #pragma unroll
        for (int mi = 0; mi < 4; ++mi)
            af[mi] = *(const f16x8*)&sA[b][(wr * 64 + mi * 16 + lrow) * 32 + lqd * 8];
        #pragma unroll
        for (int ni = 0; ni < 4; ++ni)
            bfr[ni] = *(const f16x8*)&sB[b][(wc * 64 + ni * 16 + lrow) * 32 + lqd * 8];
        #pragma unroll
        for (int mi = 0; mi < 4; ++mi)
            #pragma unroll
            for (int ni = 0; ni < 4; ++ni)
                acc[mi][ni] = __builtin_amdgcn_mfma_f32_16x16x32_f16(af[mi], bfr[ni], acc[mi][ni], 0, 0, 0);
    }

    const int which = nBase >> 8;   // 0=q, 1=k, 2=v (uniform: 128-tile within 256-group)
    const float* bias = (which == 0) ? bq : (which == 1) ? bk : bv;
    u16* dst = (which == 0) ? qb : (which == 1) ? kb : vb;
    #pragma unroll
    for (int ni = 0; ni < 4; ++ni) {
        const int cg = (nBase & 255) + wc * 64 + ni * 16;   // 16-aligned in [0,256)
        const int head = cg >> 5;
        const int d = (cg & 31) + lrow;                      // (cg&31) in {0,16}
        const float bz = bias[cg + lrow];
        u16* dh = dst + (size_t)head * T_TOK * 32;
        #pragma unroll
        for (int mi = 0; mi < 4; ++mi) {
            #pragma unroll
            for (int r = 0; r < 4; ++r) {
                const int row = mBase + wr * 64 + mi * 16 + lqd * 4 + r;
                dh[(size_t)row * 32 + d] = f16b(acc[mi][ni][r] + bz);
            }
        }
    }
}

// ---------------------------------------------------------------------------
// Out-projection, 64x64 tile (784 blocks), single-pass f16 MFMA, GLD16,
// double-buffered, one barrier per k-tile. XCD-chunked swizzle (784 = 8x98)
// so the 4 n-tiles of the same rows share one XCD's L2 (ao read ~once/XCD).
// ---------------------------------------------------------------------------
__global__ __launch_bounds__(256) void out_mfma(
    const u16* __restrict__ ao, const u16* __restrict__ woh,
    const float* __restrict__ bo, float* __restrict__ out) {
    __shared__ __attribute__((aligned(16))) u16 sA[2][64 * 32];
    __shared__ __attribute__((aligned(16))) u16 sB[2][64 * 32];
    const int bid = blockIdx.y * 4 + blockIdx.x;
    const int work = (bid & 7) * 98 + (bid >> 3);
    const int nBase = (work & 3) * 64;
    const int mBase = (work >> 2) * 64;
    const int tid = threadIdx.x, wv = tid >> 6, ln = tid & 63;
    const int lrow = ln & 15, lqd = ln >> 4;
    const int rA = tid >> 2, kcA = tid & 3;
    const size_t gA = (size_t)(mBase + rA) * EMB + kcA * 8;
    const size_t gB = (size_t)(nBase + rA) * EMB + kcA * 8;
    const int lA = wv * 512;

    f32x4 acc[4];
    #pragma unroll
    for (int mi = 0; mi < 4; ++mi) acc[mi] = (f32x4){0.f, 0.f, 0.f, 0.f};

    GLD16(ao  + gA, &sA[0][lA]);
    GLD16(woh + gB, &sB[0][lA]);

    for (int kt = 0; kt < 8; ++kt) {
        const int b = kt & 1;
        __syncthreads();
        if (kt < 7) {
            const int k0 = (kt + 1) * 32;
            GLD16(ao  + gA + k0, &sA[b ^ 1][lA]);
            GLD16(woh + gB + k0, &sB[b ^ 1][lA]);
        }
        f16x8 af[4];
        #pragma unroll
        for (int mi = 0; mi < 4; ++mi)
            af[mi] = *(const f16x8*)&sA[b][(mi * 16 + lrow) * 32 + lqd * 8];
        const f16x8 bf = *(const f16x8*)&sB[b][(wv * 16 + lrow) * 32 + lqd * 8];
        #pragma unroll
        for (int mi = 0; mi < 4; ++mi)
            acc[mi] = __builtin_amdgcn_mfma_f32_16x16x32_f16(af[mi], bf, acc[mi], 0, 0, 0);
    }

    const int ncol = nBase + wv * 16 + lrow;
    const float bz = bo[ncol];
    #pragma unroll
    for (int mi = 0; mi < 4; ++mi) {
        #pragma unroll
        for (int r = 0; r < 4; ++r) {
            const int row = mBase + mi * 16 + lqd * 4 + r;
            out[(size_t)row * EMB + ncol] = acc[mi][r] + bz;
        }
    }
}

// ---------------------------------------------------------------------------
// Attention, swapped-operand MFMA form: S^T = mfma(K,Q) so each lane owns
// S[qpix=lrow][cols lqd*4+r] -> softmax is lane-local (no max pass: logits
// are small, exp2 directly; masked cols -> 0), sum = 31 VALU adds + 2 shfls.
// P stored with 8 ds_write_b64 (was 32 b16); PV = mfma(V^T, P) yields O^T
// whose layout packs the epilogue into 2x 8B global stores (was 8x 2B).
// LDS 30720 B -> 5 blk/CU.
// ---------------------------------------------------------------------------
__global__ __launch_bounds__(256, 5) void attn_kernel(
    const u16* __restrict__ qb, const u16* __restrict__ kb, const u16* __restrict__ vb,
    u16* __restrict__ ao) {
    __shared__ __attribute__((aligned(16))) u16 smem[15360];   // 30720 B
    u16* sVT = smem;            // [32][VTSTR=208]  V^T (persists)
    u16* sK  = smem + 6656;     // [208][KSTR=40]   K halo, rows>=196 zero
    u16* sP  = smem + 6656;     // [4][16][PSTR=136] overlays sK after barrier 2

    const int tid = threadIdx.x;
    const int w = tid >> 6, ln = tid & 63;
    const int lrow = ln & 15, lqd = ln >> 4;
    const int img = blockIdx.z >> 3, head = blockIdx.z & 7;
    const int ty0 = blockIdx.y * 8, tx0 = blockIdx.x * 8;
    const int base8 = (28 * w) & ~7;   // {0, 24, 56, 80}

    const u16* kbh = kb + (size_t)head * (T_TOK * 32);
    const u16* vbh = vb + (size_t)head * (T_TOK * 32);
    const u16* qbh = qb + (size_t)head * (T_TOK * 32);

    // ---- stage K [p][d] (b128) and V transposed [d][p] (b16 scatter) ----
    for (int i = tid; i < 1664; i += 256) {
        const int mv = (i >= 832) ? 1 : 0;
        const int ii = i - 832 * mv;
        const int p = ii >> 2, c = ii & 3;
        const int pyh = p / 14, pxh = p - pyh * 14;
        const int gy = ty0 - 3 + pyh, gx = tx0 - 3 + pxh;
        const bool ok = (p < HALO) & ((unsigned)gy < 56u) & ((unsigned)gx < 56u);
        const size_t tt = (size_t)((img * IMG + gy) * IMG + gx) * 32;
        if (!mv) {
            u16* dstk = sK + p * KSTR + c * 8;
            if (ok) {
                *(uint4*)dstk = *(const uint4*)(kbh + tt + c * 8);
            } else {
                *(uint4*)dstk = (uint4){0u, 0u, 0u, 0u};
            }
        } else {
            u16* dv = sVT + (c * 8) * VTSTR + p;
            if (ok) {
                const uint4 u = *(const uint4*)(vbh + tt + c * 8);
                dv[0 * VTSTR] = (u16)(u.x & 0xffffu);
                dv[1 * VTSTR] = (u16)(u.x >> 16);
                dv[2 * VTSTR] = (u16)(u.y & 0xffffu);
                dv[3 * VTSTR] = (u16)(u.y >> 16);
                dv[4 * VTSTR] = (u16)(u.z & 0xffffu);
                dv[5 * VTSTR] = (u16)(u.z >> 16);
                dv[6 * VTSTR] = (u16)(u.w & 0xffffu);
                dv[7 * VTSTR] = (u16)(u.w >> 16);
            } else {
                #pragma unroll
                for (int j = 0; j < 8; ++j) dv[j * VTSTR] = 0;
            }
        }
    }

    // ---- Q fragment (row = this lane's query pixel = w*16+lrow) ----
    const int qpy = 2 * w + (lrow >> 3), qpx = lrow & 7;   // pixel within 8x8 tile
    const size_t qtok = ((size_t)img * IMG + ty0 + qpy) * IMG + tx0 + qpx;
    const f16x8 aq = *(const f16x8*)&qbh[qtok * 32 + lqd * 8];
    __syncthreads();

    // ---- QK^T swapped: ct[t] = K_tile^T side; lane holds
    //      S[qpix = lrow][col = base8 + t*16 + lqd*4 + r] ----
    f32x4 ct[8];
    #pragma unroll
    for (int t = 0; t < 8; ++t) ct[t] = (f32x4){0.f, 0.f, 0.f, 0.f};
    #pragma unroll
    for (int t = 0; t < 8; ++t) {
        const f16x8 bk = *(const f16x8*)&sK[(base8 + t * 16 + lrow) * KSTR + lqd * 8];
        ct[t] = __builtin_amdgcn_mfma_f32_16x16x32_f16(bk, aq, ct[t], 0, 0, 0);
    }

    // ---- mask + exp2 (no max pass: |logits| small, f32-safe), lane-local sum
    float ssum = 0.f;
    #pragma unroll
    for (int t = 0; t < 8; ++t) {
        #pragma unroll
        for (int r = 0; r < 4; ++r) {
            const int col = base8 + t * 16 + lqd * 4 + r;
            const int hy = col / 14, hx = col - 14 * hy;
            const bool ok = ((unsigned)(hy - qpy) < 7u) &
                            ((unsigned)(hx - qpx) < 7u) & (col < HALO);
            const float e = ok ? exp2f(ct[t][r] * SCALE2) : 0.f;
            ct[t][r] = e;
            ssum += e;
        }
    }
    ssum += __shfl_xor(ssum, 16);
    ssum += __shfl_xor(ssum, 32);
    const float inv = 1.0f / ssum;

    __syncthreads();   // all QK reads of sK done; safe to overlay with P

    // ---- P (f16) to LDS: row = qpix (lrow), 4 consecutive cols per write ----
    u16* sPw = sP + w * 16 * PSTR;
    #pragma unroll
    for (int t = 0; t < 8; ++t) {
        ushort4 pw;
        pw.x = f16b(ct[t][0]);
        pw.y = f16b(ct[t][1]);
        pw.z = f16b(ct[t][2]);
        pw.w = f16b(ct[t][3]);
        *(ushort4*)&sPw[lrow * PSTR + t * 16 + lqd * 4] = pw;
    }

    // ---- PV swapped: O^T[d][qpix] = mfma(A=V^T rows=d, B=P rows=qpix) ----
    f32x4 o0 = (f32x4){0.f, 0.f, 0.f, 0.f};
    f32x4 o1 = (f32x4){0.f, 0.f, 0.f, 0.f};
    #pragma unroll
    for (int ks = 0; ks < 4; ++ks) {
        const f16x8 ap  = *(const f16x8*)&sPw[lrow * PSTR + ks * 32 + lqd * 8];
        const f16x8 av0 = *(const f16x8*)&sVT[lrow * VTSTR + base8 + ks * 32 + lqd * 8];
        const f16x8 av1 = *(const f16x8*)&sVT[(16 + lrow) * VTSTR + base8 + ks * 32 + lqd * 8];
        o0 = __builtin_amdgcn_mfma_f32_16x16x32_f16(av0, ap, o0, 0, 0, 0);
        o1 = __builtin_amdgcn_mfma_f32_16x16x32_f16(av1, ap, o1, 0, 0, 0);
    }

    // ---- epilogue: lane holds O[qpix=lrow][d = lqd*4 + r (+16)] ----
    const size_t base = qtok * EMB + head * 32;
    ushort4 s0, s1;
    s0.x = f16b(o0[0] * inv); s0.y = f16b(o0[1] * inv);
    s0.z = f16b(o0[2] * inv); s0.w = f16b(o0[3] * inv);
    s1.x = f16b(o1[0] * inv); s1.y = f16b(o1[1] * inv);
    s1.z = f16b(o1[2] * inv); s1.w = f16b(o1[3] * inv);
    *(ushort4*)&ao[base + lqd * 4]      = s0;
    *(ushort4*)&ao[base + 16 + lqd * 4] = s1;
}

extern "C" void kernel_launch(void* const* d_in, const int* in_sizes, int n_in,
                              void* d_out, int out_size, void* d_ws, size_t ws_size,
                              hipStream_t stream) {
    const float* x  = (const float*)d_in[0];
    const float* wq = (const float*)d_in[1];
    const float* wk = (const float*)d_in[2];
    const float* wv = (const float*)d_in[3];
    const float* wo = (const float*)d_in[4];
    const float* bq = (const float*)d_in[5];
    const float* bk = (const float*)d_in[6];
    const float* bv = (const float*)d_in[7];
    const float* bo = (const float*)d_in[8];
    float* out = (float*)d_out;

    char* ws = (char*)d_ws;
    u16* xb  = (u16*)(ws);               // 6,422,528 B  f16 x
    u16* qb  = (u16*)(ws +  6422528);    // 6,422,528 B  head-blocked [8][12544][32]
    u16* kb  = (u16*)(ws + 12845056);    // 6,422,528 B  head-blocked
    u16* vb  = (u16*)(ws + 19267584);    // 6,422,528 B  head-blocked
    u16* ao  = (u16*)(ws + 25690112);    // 6,422,528 B  attn out f16 [tok][256]
    u16* wsh = (u16*)(ws + 32112640);    // 393,216 B  stacked qkv weights f16
    u16* woh = (u16*)(ws + 32505856);    // 131,072 B  wo f16 -> 32,636,928 B

    convert_kernel<<<3392, 256, 0, stream>>>(x, wq, wk, wv, wo, xb, wsh, woh);
    qkv_mfma<<<dim3(6, 98), 256, 0, stream>>>(xb, wsh, bq, bk, bv, qb, kb, vb);
    attn_kernel<<<dim3(7, 7, 32), 256, 0, stream>>>(qb, kb, vb, ao);
    out_mfma<<<dim3(4, 196), 256, 0, stream>>>(ao, woh, bo, out);
}

// Round 4
// 116.080 us; speedup vs baseline: 1.1259x; 1.0402x over previous
//
#include <hip/hip_runtime.h>

typedef unsigned int u32;
typedef unsigned short u16;
typedef _Float16 f16;
typedef __attribute__((ext_vector_type(8))) _Float16 f16x8;
typedef __attribute__((ext_vector_type(4))) float f32x4;

#define T_TOK 12544   // 4*56*56
#define EMB   256
#define IMG   56
// SCALE * log2(e): softmax via exp2 is mathematically identical
#define SCALE2 0.25503486f
#define HALO  196
#define KSTR  40      // sK row stride (u16)
#define VTSTR 208     // sVT row stride (u16) — must stay %8==0 for b128 PV reads
#define PSTR  136     // sP row stride (u16): 128-col window + 8 pad (17x16B rows)

__device__ __forceinline__ u16 f16b(float f) {
    const f16 h = (f16)f;                 // v_cvt_f16_f32, RTNE
    return __builtin_bit_cast(u16, h);
}
__device__ __forceinline__ u32 pk2(float lo, float hi) {
    return (u32)f16b(lo) | ((u32)f16b(hi) << 16);
}
__device__ __forceinline__ uint4 pk16(const float4 a, const float4 b) {
    uint4 r;
    r.x = pk2(a.x, a.y); r.y = pk2(a.z, a.w);
    r.z = pk2(b.x, b.y); r.w = pk2(b.z, b.w);
    return r;
}

// async global->LDS, 16B/lane; LDS dest must be wave-uniform base + lane*16
#define GLD16(g, l) __builtin_amdgcn_global_load_lds( \
    (const __attribute__((address_space(1))) u32*)(g), \
    (__attribute__((address_space(3))) u32*)(l), 16, 0, 0)

// ---------------------------------------------------------------------------
// QKV GEMM, 128x128 tile (588 blocks): 4 waves, each wave a 64x64 quadrant
// (acc 4x4). A and B staged DIRECTLY from f32 (x / wq|wk|wv): 8 dwordx4
// loads issued at phase start, RTNE-cvt + 4 linear ds_write_b128 after the
// MFMA phase (loads' latency hides under MFMA). Double-buffered, 1 barrier
// per k-tile. XCD-chunked bijective swizzle (588 = 4x74 + 4x73). Output
// HEAD-BLOCKED [head][token][32] f16.
// ---------------------------------------------------------------------------
__global__ __launch_bounds__(256) void qkv_mfma(
    const float* __restrict__ xf,
    const float* __restrict__ wq, const float* __restrict__ wk, const float* __restrict__ wv,
    const float* __restrict__ bq, const float* __restrict__ bk, const float* __restrict__ bv,
    u16* __restrict__ qb, u16* __restrict__ kb, u16* __restrict__ vb) {
    __shared__ __attribute__((aligned(16))) u16 sA[2][128 * 32];
    __shared__ __attribute__((aligned(16))) u16 sB[2][128 * 32];
    const int bid = blockIdx.y * 6 + blockIdx.x;
    const int xcd = bid & 7, loc = bid >> 3;
    const int work = (xcd < 4 ? xcd * 74 : 296 + (xcd - 4) * 73) + loc;
    const int nBase = (work % 6) * 128;            // 0..767 (stacked qkv)
    const int mBase = (work / 6) * 128;
    const int tid = threadIdx.x, wv_ = tid >> 6, ln = tid & 63;
    const int lrow = ln & 15, lqd = ln >> 4;
    const int wr = wv_ >> 1, wc = wv_ & 1;         // wave quadrant (2x2)

    const int which = nBase >> 8;   // 0=q, 1=k, 2=v (uniform per block)
    const float* wsrc = (which == 0) ? wq : (which == 1) ? wk : wv;
    const int nrow0 = nBase & 255;

    // staging map: thread -> (row = tid>>2 and +64, cols (tid&3)*8 .. +8)
    const int arow = tid >> 2, acol = (tid & 3) * 8;
    const float* gAf = xf   + (size_t)(mBase + arow) * EMB + acol;
    const float* gBf = wsrc + (size_t)(nrow0 + arow) * EMB + acol;
    const int so = tid * 8;                        // u16 offset (linear, conflict-free)

    f32x4 acc[4][4];
    #pragma unroll
    for (int mi = 0; mi < 4; ++mi)
        #pragma unroll
        for (int ni = 0; ni < 4; ++ni) acc[mi][ni] = (f32x4){0.f, 0.f, 0.f, 0.f};

    // prologue: stage k-tile 0 into buffer 0
    {
        const float4 ra0 = *(const float4*)(gAf);
        const float4 ra1 = *(const float4*)(gAf + 4);
        const float4 ra2 = *(const float4*)(gAf + 64 * EMB);
        const float4 ra3 = *(const float4*)(gAf + 64 * EMB + 4);
        const float4 rb0 = *(const float4*)(gBf);
        const float4 rb1 = *(const float4*)(gBf + 4);
        const float4 rb2 = *(const float4*)(gBf + 64 * EMB);
        const float4 rb3 = *(const float4*)(gBf + 64 * EMB + 4);
        *(uint4*)&sA[0][so]        = pk16(ra0, ra1);
        *(uint4*)&sA[0][2048 + so] = pk16(ra2, ra3);
        *(uint4*)&sB[0][so]        = pk16(rb0, rb1);
        *(uint4*)&sB[0][2048 + so] = pk16(rb2, rb3);
    }

    for (int kt = 0; kt < 8; ++kt) {
        const int b = kt & 1;
        __syncthreads();
        float4 ra0, ra1, ra2, ra3, rb0, rb1, rb2, rb3;
        if (kt < 7) {
            const int k0 = (kt + 1) * 32;
            ra0 = *(const float4*)(gAf + k0);
            ra1 = *(const float4*)(gAf + k0 + 4);
            ra2 = *(const float4*)(gAf + k0 + 64 * EMB);
            ra3 = *(const float4*)(gAf + k0 + 64 * EMB + 4);
            rb0 = *(const float4*)(gBf + k0);
            rb1 = *(const float4*)(gBf + k0 + 4);
            rb2 = *(const float4*)(gBf + k0 + 64 * EMB);
            rb3 = *(const float4*)(gBf + k0 + 64 * EMB + 4);
        }
        f16x8 af[4], bfr[4];
        #pragma unroll
        for (int mi = 0; mi < 4; ++mi)
            af[mi] = *(const f16x8*)&sA[b][(wr * 64 + mi * 16 + lrow) * 32 + lqd * 8];
        #pragma unroll
        for (int ni = 0; ni < 4; ++ni)
            bfr[ni] = *(const f16x8*)&sB[b][(wc * 64 + ni * 16 + lrow) * 32 + lqd * 8];
        #pragma unroll
        for (int mi = 0; mi < 4; ++mi)
            #pragma unroll
            for (int ni = 0; ni < 4; ++ni)
                acc[mi][ni] = __builtin_amdgcn_mfma_f32_16x16x32_f16(af[mi], bfr[ni], acc[mi][ni], 0, 0, 0);
        if (kt < 7) {
            *(uint4*)&sA[b ^ 1][so]        = pk16(ra0, ra1);
            *(uint4*)&sA[b ^ 1][2048 + so] = pk16(ra2, ra3);
            *(uint4*)&sB[b ^ 1][so]        = pk16(rb0, rb1);
            *(uint4*)&sB[b ^ 1][2048 + so] = pk16(rb2, rb3);
        }
    }

    const float* bias = (which == 0) ? bq : (which == 1) ? bk : bv;
    u16* dst = (which == 0) ? qb : (which == 1) ? kb : vb;
    #pragma unroll
    for (int ni = 0; ni < 4; ++ni) {
        const int cg = nrow0 + wc * 64 + ni * 16;            // 16-aligned in [0,256)
        const int head = cg >> 5;
        const int d = (cg & 31) + lrow;                      // (cg&31) in {0,16}
        const float bz = bias[cg + lrow];
        u16* dh = dst + (size_t)head * T_TOK * 32;
        #pragma unroll
        for (int mi = 0; mi < 4; ++mi) {
            #pragma unroll
            for (int r = 0; r < 4; ++r) {
                const int row = mBase + wr * 64 + mi * 16 + lqd * 4 + r;
                dh[(size_t)row * 32 + d] = f16b(acc[mi][ni][r] + bz);
            }
        }
    }
}

// ---------------------------------------------------------------------------
// Out-projection, 64x64 tile (784 blocks): A = ao (f16) via GLD16; B = wo
// staged directly from f32 (2 dwordx4 + 1 ds_write_b128). Double-buffered,
// one barrier per k-tile. XCD-chunked swizzle (784 = 8x98).
// ---------------------------------------------------------------------------
__global__ __launch_bounds__(256) void out_mfma(
    const u16* __restrict__ ao, const float* __restrict__ wo,
    const float* __restrict__ bo, float* __restrict__ out) {
    __shared__ __attribute__((aligned(16))) u16 sA[2][64 * 32];
    __shared__ __attribute__((aligned(16))) u16 sB[2][64 * 32];
    const int bid = blockIdx.y * 4 + blockIdx.x;
    const int work = (bid & 7) * 98 + (bid >> 3);
    const int nBase = (work & 3) * 64;
    const int mBase = (work >> 2) * 64;
    const int tid = threadIdx.x, wv_ = tid >> 6, ln = tid & 63;
    const int lrow = ln & 15, lqd = ln >> 4;
    const int rA = tid >> 2, kcA = tid & 3;
    const size_t gA = (size_t)(mBase + rA) * EMB + kcA * 8;
    const int lA = wv_ * 512;

    const int brow = tid >> 2, bcol = (tid & 3) * 8;
    const float* gBf = wo + (size_t)(nBase + brow) * EMB + bcol;
    const int so = tid * 8;

    f32x4 acc[4];
    #pragma unroll
    for (int mi = 0; mi < 4; ++mi) acc[mi] = (f32x4){0.f, 0.f, 0.f, 0.f};

    GLD16(ao + gA, &sA[0][lA]);
    {
        const float4 rb0 = *(const float4*)(gBf);
        const float4 rb1 = *(const float4*)(gBf + 4);
        *(uint4*)&sB[0][so] = pk16(rb0, rb1);
    }

    for (int kt = 0; kt < 8; ++kt) {
        const int b = kt & 1;
        __syncthreads();
        float4 rb0, rb1;
        if (kt < 7) {
            const int k0 = (kt + 1) * 32;
            GLD16(ao + gA + k0, &sA[b ^ 1][lA]);
            rb0 = *(const float4*)(gBf + k0);
            rb1 = *(const float4*)(gBf + k0 + 4);
        }
        f16x8 af[4];
        #pragma unroll
        for (int mi = 0; mi < 4; ++mi)
            af[mi] = *(const f16x8*)&sA[b][(mi * 16 + lrow) * 32 + lqd * 8];
        const f16x8 bf = *(const f16x8*)&sB[b][(wv_ * 16 + lrow) * 32 + lqd * 8];
        #pragma unroll
        for (int mi = 0; mi < 4; ++mi)
            acc[mi] = __builtin_amdgcn_mfma_f32_16x16x32_f16(af[mi], bf, acc[mi], 0, 0, 0);
        if (kt < 7) {
            *(uint4*)&sB[b ^ 1][so] = pk16(rb0, rb1);
        }
    }

    const int ncol = nBase + wv_ * 16 + lrow;
    const float bz = bo[ncol];
    #pragma unroll
    for (int mi = 0; mi < 4; ++mi) {
        #pragma unroll
        for (int r = 0; r < 4; ++r) {
            const int row = mBase + mi * 16 + lqd * 4 + r;
            out[(size_t)row * EMB + ncol] = acc[mi][r] + bz;
        }
    }
}

// ---------------------------------------------------------------------------
// Attention, swapped-operand MFMA form: S^T = mfma(K,Q) so each lane owns
// S[qpix=lrow][cols lqd*4+r] -> softmax lane-local (no max pass), sum = 31
// VALU adds + 2 shfls. P stored with 8 ds_write_b64; PV = mfma(V^T, P) gives
// O^T -> 2x 8B global stores. V^T staged PAIR-WISE: 8 ds_write_b32 per two
// pixels (halo rows are 14 wide = even, pairs never straddle rows) — halves
// the V-scatter DS instruction count. LDS 30720 B -> 5 blk/CU.
// ---------------------------------------------------------------------------
__global__ __launch_bounds__(256, 5) void attn_kernel(
    const u16* __restrict__ qb, const u16* __restrict__ kb, const u16* __restrict__ vb,
    u16* __restrict__ ao) {
    __shared__ __attribute__((aligned(16))) u16 smem[15360];   // 30720 B
    u16* sVT = smem;            // [32][VTSTR=208]  V^T (persists)
    u16* sK  = smem + 6656;     // [208][KSTR=40]   K halo, rows>=196 zero
    u16* sP  = smem + 6656;     // [4][16][PSTR=136] overlays sK after barrier 2

    const int tid = threadIdx.x;
    const int w = tid >> 6, ln = tid & 63;
    const int lrow = ln & 15, lqd = ln >> 4;
    const int img = blockIdx.z >> 3, head = blockIdx.z & 7;
    const int ty0 = blockIdx.y * 8, tx0 = blockIdx.x * 8;
    const int base8 = (28 * w) & ~7;   // {0, 24, 56, 80}

    const u16* kbh = kb + (size_t)head * (T_TOK * 32);
    const u16* vbh = vb + (size_t)head * (T_TOK * 32);
    const u16* qbh = qb + (size_t)head * (T_TOK * 32);

    // ---- stage K [p][d] (b128) and V^T [d][p] (pair-wise b32 scatter) ----
    for (int i = tid; i < 1248; i += 256) {
        if (i < 832) {
            const int p = i >> 2, c = i & 3;
            const int pyh = p / 14, pxh = p - pyh * 14;
            const int gy = ty0 - 3 + pyh, gx = tx0 - 3 + pxh;
            const bool ok = (p < HALO) & ((unsigned)gy < 56u) & ((unsigned)gx < 56u);
            u16* dstk = sK + p * KSTR + c * 8;
            if (ok) {
                const size_t tt = (size_t)((img * IMG + gy) * IMG + gx) * 32;
                *(uint4*)dstk = *(const uint4*)(kbh + tt + c * 8);
            } else {
                *(uint4*)dstk = (uint4){0u, 0u, 0u, 0u};
            }
        } else {
            const int j = i - 832;          // 0..415
            const int pp = j >> 2, c = j & 3;
            const int p0 = pp * 2;          // pixels p0, p0+1 (same halo row)
            const int pyh = p0 / 14, pxh = p0 - pyh * 14;
            const int gy = ty0 - 3 + pyh, gx = tx0 - 3 + pxh;
            const bool oky = (p0 < HALO) & ((unsigned)gy < 56u);
            const bool ok0 = oky & ((unsigned)gx < 56u);
            const bool ok1 = oky & ((unsigned)(gx + 1) < 56u);
            const long long tt = (long long)((img * IMG + gy) * IMG + gx) * 32;
            const uint4 u0 = ok0 ? *(const uint4*)(vbh + tt + c * 8)
                                 : (uint4){0u, 0u, 0u, 0u};
            const uint4 u1 = ok1 ? *(const uint4*)(vbh + tt + 32 + c * 8)
                                 : (uint4){0u, 0u, 0u, 0u};
            u16* dv = sVT + (c * 8) * VTSTR + p0;
            *(u32*)&dv[0 * VTSTR] = (u0.x & 0xffffu) | (u1.x << 16);
            *(u32*)&dv[1 * VTSTR] = (u0.x >> 16)     | (u1.x & 0xffff0000u);
            *(u32*)&dv[2 * VTSTR] = (u0.y & 0xffffu) | (u1.y << 16);
            *(u32*)&dv[3 * VTSTR] = (u0.y >> 16)     | (u1.y & 0xffff0000u);
            *(u32*)&dv[4 * VTSTR] = (u0.z & 0xffffu) | (u1.z << 16);
            *(u32*)&dv[5 * VTSTR] = (u0.z >> 16)     | (u1.z & 0xffff0000u);
            *(u32*)&dv[6 * VTSTR] = (u0.w & 0xffffu) | (u1.w << 16);
            *(u32*)&dv[7 * VTSTR] = (u0.w >> 16)     | (u1.w & 0xffff0000u);
        }
    }

    // ---- Q fragment (row = this lane's query pixel = w*16+lrow) ----
    const int qpy = 2 * w + (lrow >> 3), qpx = lrow & 7;   // pixel within 8x8 tile
    const size_t qtok = ((size_t)img * IMG + ty0 + qpy) * IMG + tx0 + qpx;
    const f16x8 aq = *(const f16x8*)&qbh[qtok * 32 + lqd * 8];
    __syncthreads();

    // ---- QK^T swapped: lane holds S[qpix=lrow][col = base8 + t*16 + lqd*4+r]
    f32x4 ct[8];
    #pragma unroll
    for (int t = 0; t < 8; ++t) ct[t] = (f32x4){0.f, 0.f, 0.f, 0.f};
    #pragma unroll
    for (int t = 0; t < 8; ++t) {
        const f16x8 bk = *(const f16x8*)&sK[(base8 + t * 16 + lrow) * KSTR + lqd * 8];
        ct[t] = __builtin_amdgcn_mfma_f32_16x16x32_f16(bk, aq, ct[t], 0, 0, 0);
    }

    // ---- mask + exp2 (no max pass: |logits| small, f32-safe), lane-local sum
    float ssum = 0.f;
    #pragma unroll
    for (int t = 0; t < 8; ++t) {
        #pragma unroll
        for (int r = 0; r < 4; ++r) {
            const int col = base8 + t * 16 + lqd * 4 + r;
            const int hy = col / 14, hx = col - 14 * hy;
            const bool ok = ((unsigned)(hy - qpy) < 7u) &
                            ((unsigned)(hx - qpx) < 7u) & (col < HALO);
            const float e = ok ? exp2f(ct[t][r] * SCALE2) : 0.f;
            ct[t][r] = e;
            ssum += e;
        }
    }
    ssum += __shfl_xor(ssum, 16);
    ssum += __shfl_xor(ssum, 32);
    const float inv = 1.0f / ssum;

    __syncthreads();   // all QK reads of sK done; safe to overlay with P

    // ---- P (f16) to LDS: row = qpix (lrow), 4 consecutive cols per write ----
    u16* sPw = sP + w * 16 * PSTR;
    #pragma unroll
    for (int t = 0; t < 8; ++t) {
        ushort4 pw;
        pw.x = f16b(ct[t][0]);
        pw.y = f16b(ct[t][1]);
        pw.z = f16b(ct[t][2]);
        pw.w = f16b(ct[t][3]);
        *(ushort4*)&sPw[lrow * PSTR + t * 16 + lqd * 4] = pw;
    }

    // ---- PV swapped: O^T[d][qpix] = mfma(A=V^T rows=d, B=P rows=qpix) ----
    f32x4 o0 = (f32x4){0.f, 0.f, 0.f, 0.f};
    f32x4 o1 = (f32x4){0.f, 0.f, 0.f, 0.f};
    #pragma unroll
    for (int ks = 0; ks < 4; ++ks) {
        const f16x8 ap  = *(const f16x8*)&sPw[lrow * PSTR + ks * 32 + lqd * 8];
        const f16x8 av0 = *(const f16x8*)&sVT[lrow * VTSTR + base8 + ks * 32 + lqd * 8];
        const f16x8 av1 = *(const f16x8*)&sVT[(16 + lrow) * VTSTR + base8 + ks * 32 + lqd * 8];
        o0 = __builtin_amdgcn_mfma_f32_16x16x32_f16(av0, ap, o0, 0, 0, 0);
        o1 = __builtin_amdgcn_mfma_f32_16x16x32_f16(av1, ap, o1, 0, 0, 0);
    }

    // ---- epilogue: lane holds O[qpix=lrow][d = lqd*4 + r (+16)] ----
    const size_t base = qtok * EMB + head * 32;
    ushort4 s0, s1;
    s0.x = f16b(o0[0] * inv); s0.y = f16b(o0[1] * inv);
    s0.z = f16b(o0[2] * inv); s0.w = f16b(o0[3] * inv);
    s1.x = f16b(o1[0] * inv); s1.y = f16b(o1[1] * inv);
    s1.z = f16b(o1[2] * inv); s1.w = f16b(o1[3] * inv);
    *(ushort4*)&ao[base + lqd * 4]      = s0;
    *(ushort4*)&ao[base + 16 + lqd * 4] = s1;
}

extern "C" void kernel_launch(void* const* d_in, const int* in_sizes, int n_in,
                              void* d_out, int out_size, void* d_ws, size_t ws_size,
                              hipStream_t stream) {
    const float* x  = (const float*)d_in[0];
    const float* wq = (const float*)d_in[1];
    const float* wk = (const float*)d_in[2];
    const float* wv = (const float*)d_in[3];
    const float* wo = (const float*)d_in[4];
    const float* bq = (const float*)d_in[5];
    const float* bk = (const float*)d_in[6];
    const float* bv = (const float*)d_in[7];
    const float* bo = (const float*)d_in[8];
    float* out = (float*)d_out;

    char* ws = (char*)d_ws;
    u16* qb = (u16*)(ws);                // 6,422,528 B  head-blocked [8][12544][32] f16
    u16* kb = (u16*)(ws +  6422528);     // 6,422,528 B
    u16* vb = (u16*)(ws + 12845056);     // 6,422,528 B
    u16* ao = (u16*)(ws + 19267584);     // 6,422,528 B  attn out f16 [tok][256] -> 25,690,112 B

    qkv_mfma<<<dim3(6, 98), 256, 0, stream>>>(x, wq, wk, wv, bq, bk, bv, qb, kb, vb);
    attn_kernel<<<dim3(7, 7, 32), 256, 0, stream>>>(qb, kb, vb, ao);
    out_mfma<<<dim3(4, 196), 256, 0, stream>>>(ao, wo, bo, out);
}